// Round 5
// baseline (55.007 us; speedup 1.0000x reference)
//
#include <hip/hip_runtime.h>

typedef int   int4v   __attribute__((ext_vector_type(4)));
typedef float float4v __attribute__((ext_vector_type(4)));

#define N_DIM 65536

__device__ __forceinline__ int quant8(float v) {
    int q = (int)rintf(v);           // round-half-to-even, matches jnp.round
    q = q > 127 ? 127 : q;
    q = q < -128 ? -128 : q;
    return q;
}

__device__ __forceinline__ int clamp16(int s) {
    s = s > 32767 ? 32767 : s;
    s = s < -32768 ? -32768 : s;
    return s;
}

// Pre-pass: w1/w2 are int-valued float32 in [-16,15]; pack to int8.
__global__ __launch_bounds__(256) void quant_weights(const float* __restrict__ w1,
                                                     const float* __restrict__ w2,
                                                     unsigned char* __restrict__ w1q,
                                                     unsigned char* __restrict__ w2q) {
    int idx = blockIdx.x * 256 + threadIdx.x;   // 32768 threads, 4 elems each
    const float* src;
    unsigned char* dst;
    int off;
    if (idx < 16384) { src = w1; dst = w1q; off = idx * 4; }
    else             { src = w2; dst = w2q; off = (idx - 16384) * 4; }
    float4v f = *reinterpret_cast<const float4v*>(src + off);
    unsigned int dw = (unsigned int)(((int)f.x & 0xff) | (((int)f.y & 0xff) << 8) |
                                     (((int)f.z & 0xff) << 16) | (((int)f.w & 0xff) << 24));
    *reinterpret_cast<unsigned int*>(dst + off) = dw;
}

// Fused kernel: 2 pairs of waves per 256-thread block. Each PAIR owns a
// 32-column strip; within a pair the two waves split the D/K dimension
// (128 rows each) to double device-wide occupancy vs one-wave-per-strip.
__global__ __launch_bounds__(256, 4) void qdq_main(const float* __restrict__ x,
                                                   const unsigned char* __restrict__ w1q,
                                                   const unsigned char* __restrict__ w2q,
                                                   int* __restrict__ out) {
    __shared__ unsigned char xb[2][8192];    // per pair: xq [32 n][256 d], swizzled
    __shared__ unsigned char pqb[2][8192];   // per pair: probs [32 n][256 k], swizzled
    __shared__ int   sMax[2][2][2][16];      // [pair][wave][tile][col]
    __shared__ float sSum[2][2][2][16];

    const int tid  = threadIdx.x;
    const int pid  = tid >> 7;        // pair in block: 0..1
    const int w    = (tid >> 6) & 1;  // wave in pair:  0..1 (owns d/k rows w*128..+127)
    const int lane = tid & 63;
    const int c    = lane & 15;       // MFMA col-in-tile / A row-in-rowtile
    const int g    = lane >> 4;       // MFMA k-group 0..3
    const int colbase = blockIdx.x * 64 + pid * 32;

    unsigned char* xw = xb[pid];
    unsigned char* pw = pqb[pid];

    // ---- 1. Load + quantize this wave's 128 d-rows x 32 cols (128B segments) ----
    const int rsub = lane >> 3;       // 0..7: row within 8-row group
    const int cg   = lane & 7;        // col group: floats cg*4..+3
    unsigned int W[16];
    {
        const float* xp = x + (size_t)(w * 128 + rsub) * N_DIM + colbase + cg * 4;
        #pragma unroll
        for (int i = 0; i < 16; ++i) {
            float4v v = *reinterpret_cast<const float4v*>(xp + (size_t)i * (8 * N_DIM));
            int q0 = quant8(v.x * 16.0f);
            int q1 = quant8(v.y * 16.0f);
            int q2 = quant8(v.z * 16.0f);
            int q3 = quant8(v.w * 16.0f);
            W[i] = (unsigned int)((q0 & 0xff) | ((q1 & 0xff) << 8) |
                                  ((q2 & 0xff) << 16) | ((q3 & 0xff) << 24));
        }
    }

    // Hoist GEMM1's first A-fragments (L2) above the transpose VALU phase.
    const unsigned char* a1 = w1q + (size_t)(w * 128 + c) * 256 + g * 16;
    int4v a_cur[4];
    #pragma unroll
    for (int kk = 0; kk < 4; ++kk)
        a_cur[kk] = *reinterpret_cast<const int4v*>(a1 + kk * 64);

    // ---- 2. In-register 4x4 byte transpose (partners lane^8, lane^16) ----
    const int R = rsub & 3;
    const unsigned int sel1 = (R & 1) ? 0x03070206u : 0x05010400u;
    const unsigned int sel2 = (R & 2) ? 0x07060302u : 0x01000504u;
    const int colsel = (0x3120 >> (R * 4)) & 0xF;   // {0,2,1,3}[R]
    const int n_t = cg * 4 + colsel;                // strip-local col 0..31
    const int qb  = rsub & 4;                       // d-quad base within 8-row group
    #pragma unroll
    for (int i = 0; i < 16; ++i) {
        unsigned int t = (unsigned int)__shfl_xor((int)W[i], 8);
        unsigned int Q = __builtin_amdgcn_perm(t, W[i], sel1);
        unsigned int u = (unsigned int)__shfl_xor((int)Q, 16);
        unsigned int F = __builtin_amdgcn_perm(Q, u, sel2);
        const int dbase = w * 128 + i * 8 + qb;
        *reinterpret_cast<unsigned int*>(xw + n_t * 256 + (dbase ^ ((n_t & 15) << 4))) = F;
    }
    __syncthreads();

    // ---- 3. B-fragments for GEMM1 (full 256-d from the shared pair tile) ----
    int4v bq[2][4];
    #pragma unroll
    for (int t = 0; t < 2; ++t)
        #pragma unroll
        for (int kk = 0; kk < 4; ++kk)
            bq[t][kk] = *reinterpret_cast<const int4v*>(
                xw + (t * 16 + c) * 256 + ((kk * 64 + g * 16) ^ (c << 4)));

    // ---- 4. GEMM1: this wave's 128 score rows (8 rt), A prefetch 1 ahead ----
    unsigned int scA[16], scB[16];
    int imA = -(1 << 30), imB = -(1 << 30);
    #pragma unroll
    for (int rt = 0; rt < 8; ++rt) {
        int4v a_nxt[4];
        if (rt < 7) {
            #pragma unroll
            for (int kk = 0; kk < 4; ++kk)
                a_nxt[kk] = *reinterpret_cast<const int4v*>(a1 + (rt + 1) * 4096 + kk * 64);
        }
        int4v accA = {0, 0, 0, 0}, accB = {0, 0, 0, 0};
        #pragma unroll
        for (int kk = 0; kk < 4; ++kk) {
            accA = __builtin_amdgcn_mfma_i32_16x16x64_i8(a_cur[kk], bq[0][kk], accA, 0, 0, 0);
            accB = __builtin_amdgcn_mfma_i32_16x16x64_i8(a_cur[kk], bq[1][kk], accB, 0, 0, 0);
        }
        {
            const int s0 = clamp16(accA[0]), s1 = clamp16(accA[1]);
            const int s2 = clamp16(accA[2]), s3 = clamp16(accA[3]);
            int m01 = s0 > s1 ? s0 : s1, m23 = s2 > s3 ? s2 : s3;
            int m = m01 > m23 ? m01 : m23;
            imA = imA > m ? imA : m;
            scA[2 * rt]     = (unsigned int)((s0 & 0xffff) | (s1 << 16));
            scA[2 * rt + 1] = (unsigned int)((s2 & 0xffff) | (s3 << 16));
        }
        {
            const int s0 = clamp16(accB[0]), s1 = clamp16(accB[1]);
            const int s2 = clamp16(accB[2]), s3 = clamp16(accB[3]);
            int m01 = s0 > s1 ? s0 : s1, m23 = s2 > s3 ? s2 : s3;
            int m = m01 > m23 ? m01 : m23;
            imB = imB > m ? imB : m;
            scB[2 * rt]     = (unsigned int)((s0 & 0xffff) | (s1 << 16));
            scB[2 * rt + 1] = (unsigned int)((s2 & 0xffff) | (s3 << 16));
        }
        #pragma unroll
        for (int kk = 0; kk < 4; ++kk) a_cur[kk] = a_nxt[kk];
    }

    // ---- 5. Softmax: intra-wave reduce, then cross-wave exchange via LDS ----
    {
        int o = __shfl_xor(imA, 16); imA = imA > o ? imA : o;
        o = __shfl_xor(imA, 32);     imA = imA > o ? imA : o;
        o = __shfl_xor(imB, 16);     imB = imB > o ? imB : o;
        o = __shfl_xor(imB, 32);     imB = imB > o ? imB : o;
    }
    if (g == 0) sMax[pid][w][0][c] = imA;
    if (g == 1) sMax[pid][w][1][c] = imB;
    __syncthreads();
    {
        int oA = sMax[pid][w ^ 1][0][c];
        int oB = sMax[pid][w ^ 1][1][c];
        imA = imA > oA ? imA : oA;
        imB = imB > oB ? imB : oB;
    }

    const float C = 0.0056355275034725134f;   // SCORE_SCALE * log2(e)
    float sumA = 0.0f, sumB = 0.0f;
    #pragma unroll
    for (int i = 0; i < 16; ++i) {
        sumA += exp2f((float)((int)(short)(scA[i] & 0xffffu) - imA) * C);
        sumA += exp2f((float)(((int)scA[i] >> 16) - imA) * C);
        sumB += exp2f((float)((int)(short)(scB[i] & 0xffffu) - imB) * C);
        sumB += exp2f((float)(((int)scB[i] >> 16) - imB) * C);
    }
    sumA += __shfl_xor(sumA, 16); sumA += __shfl_xor(sumA, 32);
    sumB += __shfl_xor(sumB, 16); sumB += __shfl_xor(sumB, 32);
    if (g == 0) sSum[pid][w][0][c] = sumA;
    if (g == 1) sSum[pid][w][1][c] = sumB;
    __syncthreads();
    sumA += sSum[pid][w ^ 1][0][c];
    sumB += sSum[pid][w ^ 1][1][c];
    const float qsA = 2048.0f / sumA;
    const float qsB = 2048.0f / sumB;

    // Hoist GEMM2's first A-fragments (L2) above the exp2-heavy quant phase.
    const unsigned char* a2 = w2q + (size_t)(w * 128 + c) * 256 + g * 16;
    #pragma unroll
    for (int kk = 0; kk < 4; ++kk)
        a_cur[kk] = *reinterpret_cast<const int4v*>(a2 + kk * 64);

    // ---- 6. Quantize this wave's 128 prob rows into the shared pq tile ----
    #pragma unroll
    for (int rt = 0; rt < 8; ++rt) {
        #pragma unroll
        for (int t = 0; t < 2; ++t) {
            const unsigned int w0 = t ? scB[2 * rt] : scA[2 * rt];
            const unsigned int w1 = t ? scB[2 * rt + 1] : scA[2 * rt + 1];
            const int im = t ? imB : imA;
            const float qs = t ? qsB : qsA;
            int q0 = (int)rintf(exp2f((float)((int)(short)(w0 & 0xffffu) - im) * C) * qs);
            int q1 = (int)rintf(exp2f((float)(((int)w0 >> 16) - im) * C) * qs);
            int q2 = (int)rintf(exp2f((float)((int)(short)(w1 & 0xffffu) - im) * C) * qs);
            int q3 = (int)rintf(exp2f((float)(((int)w1 >> 16) - im) * C) * qs);
            q0 = q0 > 127 ? 127 : q0;
            q1 = q1 > 127 ? 127 : q1;
            q2 = q2 > 127 ? 127 : q2;
            q3 = q3 > 127 ? 127 : q3;
            const int koff = w * 128 + rt * 16 + g * 4;
            *reinterpret_cast<unsigned int*>(
                pw + (t * 16 + c) * 256 + (koff ^ (c << 4))) =
                (unsigned int)(q0 | (q1 << 8) | (q2 << 16) | (q3 << 24));
        }
    }
    __syncthreads();

    // ---- 7. GEMM2: this wave's 128 output rows; B = full shared prob tile ----
    int4v b2[2][4];
    #pragma unroll
    for (int t = 0; t < 2; ++t)
        #pragma unroll
        for (int kk = 0; kk < 4; ++kk)
            b2[t][kk] = *reinterpret_cast<const int4v*>(
                pw + (t * 16 + c) * 256 + ((kk * 64 + g * 16) ^ (c << 4)));

    #pragma unroll
    for (int rt = 0; rt < 8; ++rt) {
        int4v a_nxt[4];
        if (rt < 7) {
            #pragma unroll
            for (int kk = 0; kk < 4; ++kk)
                a_nxt[kk] = *reinterpret_cast<const int4v*>(a2 + (rt + 1) * 4096 + kk * 64);
        }
        int4v accA = {0, 0, 0, 0}, accB = {0, 0, 0, 0};
        #pragma unroll
        for (int kk = 0; kk < 4; ++kk) {
            accA = __builtin_amdgcn_mfma_i32_16x16x64_i8(a_cur[kk], b2[0][kk], accA, 0, 0, 0);
            accB = __builtin_amdgcn_mfma_i32_16x16x64_i8(a_cur[kk], b2[1][kk], accB, 0, 0, 0);
        }
        #pragma unroll
        for (int r = 0; r < 4; ++r) {
            const size_t rowoff = (size_t)(w * 128 + rt * 16 + g * 4 + r) * N_DIM + colbase;
            out[rowoff + c]      = clamp16(accA[r]);
            out[rowoff + 16 + c] = clamp16(accB[r]);
        }
        #pragma unroll
        for (int kk = 0; kk < 4; ++kk) a_cur[kk] = a_nxt[kk];
    }
}

extern "C" void kernel_launch(void* const* d_in, const int* in_sizes, int n_in,
                              void* d_out, int out_size, void* d_ws, size_t ws_size,
                              hipStream_t stream) {
    const float* x  = (const float*)d_in[0];
    const float* w1 = (const float*)d_in[1];
    const float* w2 = (const float*)d_in[2];
    int* out = (int*)d_out;

    unsigned char* w1q = (unsigned char*)d_ws;
    unsigned char* w2q = w1q + 65536;

    quant_weights<<<128, 256, 0, stream>>>(w1, w2, w1q, w2q);
    qdq_main<<<1024, 256, 0, stream>>>(x, w1q, w2q, out);
}